// Round 18
// baseline (478.295 us; speedup 1.0000x reference)
//
#include <hip/hip_runtime.h>
#include <hip/hip_fp16.h>

#define N_NODES 50000
#define N_EDGES 800000
#define DIM 128
#define NODE_TILES 782   // ceil(50000/64)
#define EDGE_TILES 12500 // 800000/64
#define SCAN_NB 50       // 50 blocks x 1000 counts

typedef _Float16 f16;
typedef _Float16 f16x2 __attribute__((ext_vector_type(2)));
typedef _Float16 f16x4 __attribute__((ext_vector_type(4)));
typedef _Float16 f16x8 __attribute__((ext_vector_type(8)));
typedef float    f32x16 __attribute__((ext_vector_type(16)));

__device__ __forceinline__ void sfence() { __builtin_amdgcn_sched_barrier(0); }

// ---------------- 256-thread (4-wave) GEMM pieces — used by mlp_ln ----------------
__device__ __forceinline__ void load_wfrag(const f16* __restrict__ Wh, int ch, int l31, int g,
                                           f16x8 bf[2][8]) {
#pragma unroll
  for (int c = 0; c < 2; ++c)
#pragma unroll
    for (int ks = 0; ks < 8; ++ks)
      bf[c][ks] = *(const f16x8*)(Wh + ((ch * 64 + c * 32 + l31) << 7) + 16 * ks + 8 * g);
}

__device__ __forceinline__ void stage_issue(const float* __restrict__ X, long M, long base,
                                            int tid, float4 sv[8]) {
#pragma unroll
  for (int kk = 0; kk < 8; ++kk) {
    int i = tid + kk * 256;
    long row = base + (i >> 5);
    long gr = row < M ? row : (M - 1);
    sv[kk] = *(const float4*)(X + gr * DIM + (i & 31) * 4);
  }
}

__device__ __forceinline__ void stage_write(const float4 sv[8], int tid, f16* __restrict__ lds) {
#pragma unroll
  for (int kk = 0; kk < 8; ++kk) {
    int i = tid + kk * 256;
    int r = i >> 5, s8 = i & 31;
    f16x4 h;
    h[0] = (f16)sv[kk].x; h[1] = (f16)sv[kk].y; h[2] = (f16)sv[kk].z; h[3] = (f16)sv[kk].w;
    *(f16x4*)(lds + r * 128 + (((s8 >> 1) ^ (r & 15)) << 3) + ((s8 & 1) << 2)) = h;
  }
}

__device__ __forceinline__ void mfma_lds_g(const f16* __restrict__ A, int lr, int g,
                                           const f16x8 bf[2][8], f32x16 acc[2]) {
#pragma unroll
  for (int c = 0; c < 2; ++c)
#pragma unroll
    for (int k = 0; k < 16; ++k) acc[c][k] = 0.0f;
#pragma unroll
  for (int ks = 0; ks < 8; ++ks) {
    f16x8 a = *(const f16x8*)(A + lr * 128 + (((2 * ks + g) ^ (lr & 15)) << 3));
    acc[0] = __builtin_amdgcn_mfma_f32_32x32x16_f16(a, bf[0][ks], acc[0], 0, 0, 0);
    acc[1] = __builtin_amdgcn_mfma_f32_32x32x16_f16(a, bf[1][ks], acc[1], 0, 0, 0);
  }
}

// ---------------- 512-thread (8-wave) GEMM pieces — one 32x32 block per wave ------
__device__ __forceinline__ void load_wfrag1(const f16* __restrict__ Wh, int cc, int l31, int g,
                                            f16x8 bf[8]) {
#pragma unroll
  for (int ks = 0; ks < 8; ++ks)
    bf[ks] = *(const f16x8*)(Wh + ((cc * 32 + l31) << 7) + 16 * ks + 8 * g);
}

__device__ __forceinline__ void stage_issue512(const float* __restrict__ X, long M, long base,
                                               int tid, float4 sv[4]) {
#pragma unroll
  for (int kk = 0; kk < 4; ++kk) {
    int i = tid + kk * 512;
    long row = base + (i >> 5);
    long gr = row < M ? row : (M - 1);
    sv[kk] = *(const float4*)(X + gr * DIM + (i & 31) * 4);
  }
}

__device__ __forceinline__ void stage_write512(const float4 sv[4], int tid,
                                               f16* __restrict__ lds) {
#pragma unroll
  for (int kk = 0; kk < 4; ++kk) {
    int i = tid + kk * 512;
    int r = i >> 5, s8 = i & 31;
    f16x4 h;
    h[0] = (f16)sv[kk].x; h[1] = (f16)sv[kk].y; h[2] = (f16)sv[kk].z; h[3] = (f16)sv[kk].w;
    *(f16x4*)(lds + r * 128 + (((s8 >> 1) ^ (r & 15)) << 3) + ((s8 & 1) << 2)) = h;
  }
}

__device__ __forceinline__ void mfma1(const f16* __restrict__ A, int lr, int g,
                                      const f16x8 bf[8], f32x16& acc) {
#pragma unroll
  for (int k = 0; k < 16; ++k) acc[k] = 0.0f;
#pragma unroll
  for (int ks = 0; ks < 8; ++ks) {
    f16x8 a = *(const f16x8*)(A + lr * 128 + (((2 * ks + g) ^ (lr & 15)) << 3));
    acc = __builtin_amdgcn_mfma_f32_32x32x16_f16(a, bf[ks], acc, 0, 0, 0);
  }
}

template <int HALF_OUT>
__device__ __forceinline__ void gemm_store1(const f32x16& acc, long M,
                                            const float* __restrict__ Bv,
                                            void* __restrict__ OUT,
                                            long tile0, int rc, int cc, int l31, int g) {
  int col = cc * 32 + l31;
  float bv = Bv[col];
#pragma unroll
  for (int r = 0; r < 16; ++r) {
    long gm = tile0 + rc * 32 + ((r & 3) + 8 * (r >> 2) + 4 * g);
    if (gm < M) {
      float v = acc[r] + bv;
      if (HALF_OUT) ((f16*)OUT)[gm * DIM + col] = (f16)v;
      else          ((float*)OUT)[gm * DIM + col] = v;
    }
  }
}

// ---------------- fused big GEMMs, 512 threads, one tile per block ----------------
// blocks 0..781: node4 path (sequential X reads, direct stores).
// blocks 782..13281: edge path — NATURAL-order EA tile (sequential reads at BW),
//   output staged in LDS, rows SCATTER-written to dst-sorted emat[dstpos[e]]
//   (random stores are fire-and-forget; random traffic halves: 205MB f16 writes
//    vs 410MB f32 reads of the old gather).
__global__ __launch_bounds__(512, 4) void big_gemms(const float* __restrict__ X,
    const float* __restrict__ EA, const int* __restrict__ dstpos,
    const f16* __restrict__ WhAll,
    const float* __restrict__ bq, const float* __restrict__ bk,
    const float* __restrict__ bv_, const float* __restrict__ bs, const float* __restrict__ be,
    f16* __restrict__ Q, f16* __restrict__ K, f16* __restrict__ V, float* __restrict__ S,
    f16* __restrict__ emat) {
  __shared__ f16 lbuf[64 * 128];      // 16 KB
  __shared__ int dlds[64];
  int tid = threadIdx.x;
  int lane = tid & 63, w = tid >> 6;
  int rc = w >> 2, cc = w & 3, l31 = lane & 31, g = lane >> 5;
  int lr = rc * 32 + l31;

  if (blockIdx.x < NODE_TILES) {
    long tile0 = (long)blockIdx.x * 64;
    float4 sv[4];
    stage_issue512(X, N_NODES, tile0, tid, sv);
    stage_write512(sv, tid, lbuf);
    __syncthreads();
#pragma unroll 1
    for (int mat = 0; mat < 4; ++mat) {
      f16x8 bf[8];
      load_wfrag1(WhAll + mat * 16384, cc, l31, g, bf);
      f32x16 acc;
      mfma1(lbuf, lr, g, bf, acc);
      if (mat == 0)      gemm_store1<1>(acc, N_NODES, bq, Q, tile0, rc, cc, l31, g);
      else if (mat == 1) gemm_store1<1>(acc, N_NODES, bk, K, tile0, rc, cc, l31, g);
      else if (mat == 2) gemm_store1<1>(acc, N_NODES, bv_, V, tile0, rc, cc, l31, g);
      else               gemm_store1<0>(acc, N_NODES, bs, S, tile0, rc, cc, l31, g);
    }
    return;
  }

  // ---- edge path: natural-order tile, sequential EA reads, scattered emat writes ----
  long tile0 = (long)(blockIdx.x - NODE_TILES) * 64;
  float4 sv[4];
  stage_issue512(EA, (long)N_EDGES, tile0, tid, sv);
  if (tid < 64) dlds[tid] = dstpos[tile0 + tid];
  stage_write512(sv, tid, lbuf);
  __syncthreads();
  f16x8 bf[8];
  load_wfrag1(WhAll + 4 * 16384, cc, l31, g, bf);   // L2-hot
  f32x16 acc;
  mfma1(lbuf, lr, g, bf, acc);
  __syncthreads();                    // all lbuf reads done before overwrite

  {                                   // output (f16, +bias) -> lbuf, linear rows
    int col = cc * 32 + l31;
    float bv = be[col];
#pragma unroll
    for (int r = 0; r < 16; ++r) {
      int row = rc * 32 + (r & 3) + 8 * (r >> 2) + 4 * g;
      lbuf[row * 128 + col] = (f16)(acc[r] + bv);
    }
  }
  __syncthreads();

  // scatter rows: 16 lanes x 16B = 256B contiguous per row, row -> dstpos
#pragma unroll
  for (int kk = 0; kk < 2; ++kk) {
    int i = tid + kk * 512;
    int row = i >> 4, sl = i & 15;
    long dpos = dlds[row];
    *(f16x8*)(emat + dpos * 128 + sl * 8) = *(const f16x8*)(lbuf + row * 128 + sl * 8);
  }
}

// ---------------- fused MLP + LN2 (single 32 KB LDS, phase-aliased) ----------------
__global__ __launch_bounds__(256) void mlp_ln(const float* __restrict__ X,
    const f16* __restrict__ W1h, const float* __restrict__ b1,
    const f16* __restrict__ W2h, const float* __restrict__ b2,
    const float* __restrict__ gv, const float* __restrict__ bv,
    float* __restrict__ outp) {
  __shared__ float smem[64 * 128];    // 32 KB
  f16* xs = (f16*)smem;               // first 16 KB
  f16* hs = (f16*)smem + 64 * 128;    // second 16 KB
  float* wbuf = smem;                 // full 32 KB
  int tid = threadIdx.x;
  int lane = tid & 63, w = tid >> 6;
  int rc = w >> 1, ch = w & 1, l31 = lane & 31, g = lane >> 5;
  int t = blockIdx.x;
  if (t >= NODE_TILES) return;
  long tile0 = (long)t * 64;
  int lr = rc * 32 + l31;

  float4 sv[8];
  stage_issue(X, N_NODES, tile0, tid, sv);
  f16x8 bf1[2][8];
  load_wfrag(W1h, ch, l31, g, bf1);
  stage_write(sv, tid, xs);
  __syncthreads();

  f32x16 acc[2];
  mfma_lds_g(xs, lr, g, bf1, acc);
  f16x8 bf2[2][8];
  load_wfrag(W2h, ch, l31, g, bf2);

#pragma unroll
  for (int c = 0; c < 2; ++c) {
    int col = ch * 64 + c * 32 + l31;
    float bb = b1[col];
#pragma unroll
    for (int r = 0; r < 16; ++r) {
      int row = rc * 32 + (r & 3) + 8 * (r >> 2) + 4 * g;
      float v = acc[c][r] + bb;
      v = v / (1.0f + __expf(-v));
      hs[row * 128 + (((col >> 3) ^ (row & 15)) << 3) + (col & 7)] = (f16)v;
    }
  }
  __syncthreads();

  f32x16 a2[2];
  mfma_lds_g(hs, lr, g, bf2, a2);
  __syncthreads();

#pragma unroll
  for (int c = 0; c < 2; ++c) {
    int col = ch * 64 + c * 32 + l31;
    float bb = b2[col];
#pragma unroll
    for (int r = 0; r < 16; ++r) {
      int row = rc * 32 + (r & 3) + 8 * (r >> 2) + 4 * g;
      wbuf[row * 128 + col] = a2[c][r] + bb;
    }
  }
  __syncthreads();

  float2 gg = *(const float2*)(gv + 2 * lane);
  float2 bb2 = *(const float2*)(bv + 2 * lane);
#pragma unroll 1
  for (int rr = 0; rr < 16; ++rr) {
    int row = w * 16 + rr;
    long gm = tile0 + row;
    if (gm >= N_NODES) break;
    float2 x;
    x.x = wbuf[row * 128 + 2 * lane];
    x.y = wbuf[row * 128 + 2 * lane + 1];
    float sm = x.x + x.y;
    for (int m = 1; m < 64; m <<= 1) sm += __shfl_xor(sm, m);
    float mu = sm * (1.f / 128.f);
    float dx = x.x - mu, dy = x.y - mu;
    float ss = dx * dx + dy * dy;
    for (int m = 1; m < 64; m <<= 1) ss += __shfl_xor(ss, m);
    float r = rsqrtf(ss * (1.f / 128.f) + 1e-5f);
    float2 bs = *(const float2*)(X + gm * DIM + 2 * lane);
    float2 o;
    o.x = bs.x + dx * r * gg.x + bb2.x;
    o.y = bs.y + dy * r * gg.y + bb2.y;
    *(float2*)(outp + gm * DIM + 2 * lane) = o;
  }
}

// ---------------- CSR build (parallel scan) + weight convert fused into hist ----------
__global__ void hist_conv_k(const int* __restrict__ ei, int* __restrict__ counts,
                            const float* __restrict__ a0, const float* __restrict__ a1,
                            const float* __restrict__ a2, const float* __restrict__ a3,
                            const float* __restrict__ a4, const float* __restrict__ a5,
                            const float* __restrict__ a6, f16* __restrict__ dst) {
  long gid = blockIdx.x * 256L + threadIdx.x;
  if (gid < 7 * 16384) {
    int mat = (int)(gid >> 14), el = (int)(gid & 16383);
    const float* s = (mat == 0) ? a0 : (mat == 1) ? a1 : (mat == 2) ? a2 : (mat == 3) ? a3
                   : (mat == 4) ? a4 : (mat == 5) ? a5 : a6;
    dst[gid] = (f16)s[el];
  }
  for (long e = gid; e < N_EDGES; e += 1024L * 256)
    atomicAdd(&counts[ei[N_EDGES + e]], 1);
}

__global__ __launch_bounds__(1024) void blocksum_k(const int* __restrict__ counts,
                                                   int* __restrict__ bsum) {
  __shared__ int sd[1024];
  int t = threadIdx.x, b = blockIdx.x;
  int v = (t < 1000) ? counts[b * 1000 + t] : 0;
  sd[t] = v; __syncthreads();
  for (int off = 512; off > 0; off >>= 1) {
    if (t < off) sd[t] += sd[t + off];
    __syncthreads();
  }
  if (t == 0) bsum[b] = sd[0];
}

__global__ void scan_small(const int* __restrict__ bsum, int* __restrict__ boff,
                           int* __restrict__ offs) {
  if (threadIdx.x == 0) {
    int run = 0;
    for (int b = 0; b < SCAN_NB; ++b) { boff[b] = run; run += bsum[b]; }
    boff[SCAN_NB] = run;
    offs[N_NODES] = run;
  }
}

__global__ __launch_bounds__(1024) void expand_k(const int* __restrict__ counts,
                                                 const int* __restrict__ boff,
                                                 int* __restrict__ offs, int* __restrict__ cursor) {
  __shared__ int sd[1024];
  int t = threadIdx.x, b = blockIdx.x;
  int v = (t < 1000) ? counts[b * 1000 + t] : 0;
  sd[t] = v; __syncthreads();
  for (int off = 1; off < 1024; off <<= 1) {
    int x = (t >= off) ? sd[t - off] : 0;
    __syncthreads();
    sd[t] += x;
    __syncthreads();
  }
  if (t < 1000) {
    int o = boff[b] + sd[t] - v;
    int idx = b * 1000 + t;
    offs[idx] = o;
    cursor[idx] = o;
  }
}

// scatter: srcs[pos]=src node (dst-sorted); dstpos[e]=pos (inverse permutation)
__global__ void scatter_k(const int* __restrict__ ei, int* __restrict__ cursor,
                          int* __restrict__ srcs, int* __restrict__ dstpos) {
  for (long e = blockIdx.x * (long)blockDim.x + threadIdx.x; e < N_EDGES;
       e += (long)gridDim.x * blockDim.x) {
    int d = ei[N_EDGES + e];
    int pos = atomicAdd(&cursor[d], 1);
    srcs[pos] = ei[e];
    dstpos[e] = pos;
  }
}

// ---------------- fused attention + softmax + LN1, 4 edges/iteration ----------------
__global__ __launch_bounds__(256) void attn_ln(const int* __restrict__ offs,
    const int* __restrict__ srcs, const f16* __restrict__ emat, const f16* __restrict__ Qn,
    const f16* __restrict__ Kn, const f16* __restrict__ Vn,
    const float* __restrict__ Skip, const float* __restrict__ base,
    const float* __restrict__ gv, const float* __restrict__ bv,
    float* __restrict__ outp) {
  int n = blockIdx.x * 4 + (threadIdx.x >> 6);
  if (n >= N_NODES) return;
  int lane = threadIdx.x & 63;
  int grp = lane >> 4, li = lane & 15;
  int c8 = 8 * li;

  float q[8];
  {
    f16x8 qv = *(const f16x8*)(Qn + (long)n * DIM + c8);
#pragma unroll
    for (int k = 0; k < 8; ++k) q[k] = (float)qv[k];
  }

  int rs = offs[n], re = offs[n + 1];
  float a[8];
#pragma unroll
  for (int k = 0; k < 8; ++k) a[k] = 0.f;
  float den = 0.f;

  if (rs < re) {
    int e0 = rs + grp;
    int sCur = srcs[(e0 < re) ? e0 : (re - 1)];
    for (int i = rs; i < re; i += 4) {
      int ei_ = i + grp;
      bool valid = ei_ < re;
      int ec = valid ? ei_ : (re - 1);
      int s = sCur;
      int en = ei_ + 4;
      sCur = srcs[(en < re) ? en : (re - 1)];
      f16x8 e8 = *(const f16x8*)(emat + (long)ec * DIM + c8);
      f16x8 k8 = *(const f16x8*)(Kn + (long)s * DIM + c8);
      f16x8 v8 = *(const f16x8*)(Vn + (long)s * DIM + c8);
      float p = 0.f;
#pragma unroll
      for (int k = 0; k < 8; ++k) p += q[k] * ((float)k8[k] + (float)e8[k]);
      p += __shfl_xor(p, 1);
      float ex = valid ? __expf(p * 0.25f) : 0.f;
      den += ex;
#pragma unroll
      for (int k = 0; k < 8; ++k) a[k] += ex * ((float)e8[k] + (float)v8[k]);
    }
  }
#pragma unroll
  for (int k = 0; k < 8; ++k) {
    a[k] += __shfl_xor(a[k], 16);
    a[k] += __shfl_xor(a[k], 32);
  }
  den += __shfl_xor(den, 16);
  den += __shfl_xor(den, 32);

  float inv = 1.f / (den + 1e-16f);
  float x[8];
  {
    float4 sk0 = *(const float4*)(Skip + (long)n * DIM + c8);
    float4 sk1 = *(const float4*)(Skip + (long)n * DIM + c8 + 4);
    x[0] = a[0] * inv + sk0.x; x[1] = a[1] * inv + sk0.y;
    x[2] = a[2] * inv + sk0.z; x[3] = a[3] * inv + sk0.w;
    x[4] = a[4] * inv + sk1.x; x[5] = a[5] * inv + sk1.y;
    x[6] = a[6] * inv + sk1.z; x[7] = a[7] * inv + sk1.w;
  }

  float sm = 0.f;
#pragma unroll
  for (int k = 0; k < 8; ++k) sm += x[k];
  for (int m = 1; m < 16; m <<= 1) sm += __shfl_xor(sm, m);
  float mu = sm * (1.f / 128.f);
  float d[8], ss = 0.f;
#pragma unroll
  for (int k = 0; k < 8; ++k) { d[k] = x[k] - mu; ss += d[k] * d[k]; }
  for (int m = 1; m < 16; m <<= 1) ss += __shfl_xor(ss, m);
  float r = rsqrtf(ss * (1.f / 128.f) + 1e-5f);

  if (grp == 0) {
    float4 g0 = *(const float4*)(gv + c8);
    float4 g1 = *(const float4*)(gv + c8 + 4);
    float4 b0 = *(const float4*)(bv + c8);
    float4 b1 = *(const float4*)(bv + c8 + 4);
    float4 s0 = *(const float4*)(base + (long)n * DIM + c8);
    float4 s1 = *(const float4*)(base + (long)n * DIM + c8 + 4);
    float4 o0, o1;
    o0.x = s0.x + d[0] * r * g0.x + b0.x;
    o0.y = s0.y + d[1] * r * g0.y + b0.y;
    o0.z = s0.z + d[2] * r * g0.z + b0.z;
    o0.w = s0.w + d[3] * r * g0.w + b0.w;
    o1.x = s1.x + d[4] * r * g1.x + b1.x;
    o1.y = s1.y + d[5] * r * g1.y + b1.y;
    o1.z = s1.z + d[6] * r * g1.z + b1.z;
    o1.w = s1.w + d[7] * r * g1.w + b1.w;
    *(float4*)(outp + (long)n * DIM + c8) = o0;
    *(float4*)(outp + (long)n * DIM + c8 + 4) = o1;
  }
}

// ---------------- launch ----------------
extern "C" void kernel_launch(void* const* d_in, const int* in_sizes, int n_in,
                              void* d_out, int out_size, void* d_ws, size_t ws_size,
                              hipStream_t stream) {
  (void)in_sizes; (void)n_in; (void)out_size; (void)ws_size;
  const int*   ei  = (const int*)d_in[0];
  const float* x0  = (const float*)d_in[1];
  const float* ea  = (const float*)d_in[2];
  const float* Wq  = (const float*)d_in[3];  const float* bq = (const float*)d_in[4];
  const float* Wk  = (const float*)d_in[5];  const float* bk = (const float*)d_in[6];
  const float* Wv  = (const float*)d_in[7];  const float* bv = (const float*)d_in[8];
  const float* We  = (const float*)d_in[9];  const float* be = (const float*)d_in[10];
  const float* Wsk = (const float*)d_in[11]; const float* bsk = (const float*)d_in[12];
  const float* W1  = (const float*)d_in[13]; const float* b1 = (const float*)d_in[14];
  const float* W2  = (const float*)d_in[15]; const float* b2 = (const float*)d_in[16];
  const float* g1  = (const float*)d_in[17]; const float* lb1 = (const float*)d_in[18];
  const float* g2  = (const float*)d_in[19]; const float* lb2 = (const float*)d_in[20];

  char* ws = (char*)d_ws;
  f16*   Qn     = (f16*)(ws + 0);              // 12.8M
  f16*   Kn     = (f16*)(ws + 12800000L);      // 12.8M
  f16*   Vn     = (f16*)(ws + 25600000L);      // 12.8M
  float* Skip   = (float*)(ws + 38400000L);    // 25.6M -> 64,000,000
  int*   offs   = (int*)(ws + 64000000L);      // 200,192
  int*   cursor = (int*)(ws + 64200192L);      // 200,192
  int*   counts = (int*)(ws + 64429568L);      // 200,000
  int*   bsum   = (int*)(ws + 64629760L);      // 512 B
  int*   boff   = bsum + 64;
  int*   srcs   = (int*)(ws + 64630272L);      // 3.2M
  int*   dstpos = (int*)(ws + 67830272L);      // 3.2M
  f16*   emat   = (f16*)(ws + 71030272L);      // 204.8M (dst-sorted)
  float* node1  = (float*)(ws + 275830272L);   // 25.6M
  f16*   WhAll  = (f16*)(ws + 301430272L);     // 229,376 own slot

  (void)hipMemsetAsync(counts, 0, N_NODES * sizeof(int), stream);
  hist_conv_k<<<1024, 256, 0, stream>>>(ei, counts, Wq, Wk, Wv, Wsk, We, W1, W2, WhAll);
  blocksum_k<<<SCAN_NB, 1024, 0, stream>>>(counts, bsum);
  scan_small<<<1, 64, 0, stream>>>(bsum, boff, offs);
  expand_k<<<SCAN_NB, 1024, 0, stream>>>(counts, boff, offs, cursor);
  scatter_k<<<1024, 256, 0, stream>>>(ei, cursor, srcs, dstpos);

  big_gemms<<<NODE_TILES + EDGE_TILES, 512, 0, stream>>>(
      x0, ea, dstpos, WhAll, bq, bk, bv, bsk, be, Qn, Kn, Vn, Skip, emat);
  attn_ln<<<12500, 256, 0, stream>>>(offs, srcs, emat, Qn, Kn, Vn, Skip, x0, g1, lb1, node1);
  mlp_ln<<<NODE_TILES, 256, 0, stream>>>(node1, WhAll + 5 * 16384, b1,
                                         WhAll + 6 * 16384, b2, g2, lb2, (float*)d_out);
}

// Round 19
// 445.169 us; speedup vs baseline: 1.0744x; 1.0744x over previous
//
#include <hip/hip_runtime.h>
#include <hip/hip_fp16.h>

#define N_NODES 50000
#define N_EDGES 800000
#define DIM 128
#define NODE_TILES 782   // ceil(50000/64)
#define EDGE_TILES 12500 // 800000/64
#define SCAN_NB 50       // 50 blocks x 1000 counts

typedef _Float16 f16;
typedef _Float16 f16x2 __attribute__((ext_vector_type(2)));
typedef _Float16 f16x4 __attribute__((ext_vector_type(4)));
typedef _Float16 f16x8 __attribute__((ext_vector_type(8)));
typedef float    f32x16 __attribute__((ext_vector_type(16)));

__device__ __forceinline__ void sfence() { __builtin_amdgcn_sched_barrier(0); }

// ---------------- 256-thread (4-wave) GEMM pieces — used by mlp_ln ----------------
__device__ __forceinline__ void load_wfrag(const f16* __restrict__ Wh, int ch, int l31, int g,
                                           f16x8 bf[2][8]) {
#pragma unroll
  for (int c = 0; c < 2; ++c)
#pragma unroll
    for (int ks = 0; ks < 8; ++ks)
      bf[c][ks] = *(const f16x8*)(Wh + ((ch * 64 + c * 32 + l31) << 7) + 16 * ks + 8 * g);
}

__device__ __forceinline__ void stage_issue(const float* __restrict__ X, long M, long base,
                                            int tid, float4 sv[8]) {
#pragma unroll
  for (int kk = 0; kk < 8; ++kk) {
    int i = tid + kk * 256;
    long row = base + (i >> 5);
    long gr = row < M ? row : (M - 1);
    sv[kk] = *(const float4*)(X + gr * DIM + (i & 31) * 4);
  }
}

__device__ __forceinline__ void stage_write(const float4 sv[8], int tid, f16* __restrict__ lds) {
#pragma unroll
  for (int kk = 0; kk < 8; ++kk) {
    int i = tid + kk * 256;
    int r = i >> 5, s8 = i & 31;
    f16x4 h;
    h[0] = (f16)sv[kk].x; h[1] = (f16)sv[kk].y; h[2] = (f16)sv[kk].z; h[3] = (f16)sv[kk].w;
    *(f16x4*)(lds + r * 128 + (((s8 >> 1) ^ (r & 15)) << 3) + ((s8 & 1) << 2)) = h;
  }
}

__device__ __forceinline__ void mfma_lds_g(const f16* __restrict__ A, int lr, int g,
                                           const f16x8 bf[2][8], f32x16 acc[2]) {
#pragma unroll
  for (int c = 0; c < 2; ++c)
#pragma unroll
    for (int k = 0; k < 16; ++k) acc[c][k] = 0.0f;
#pragma unroll
  for (int ks = 0; ks < 8; ++ks) {
    f16x8 a = *(const f16x8*)(A + lr * 128 + (((2 * ks + g) ^ (lr & 15)) << 3));
    acc[0] = __builtin_amdgcn_mfma_f32_32x32x16_f16(a, bf[0][ks], acc[0], 0, 0, 0);
    acc[1] = __builtin_amdgcn_mfma_f32_32x32x16_f16(a, bf[1][ks], acc[1], 0, 0, 0);
  }
}

// ---------------- 512-thread (8-wave) GEMM pieces — one 32x32 block per wave ------
__device__ __forceinline__ void load_wfrag1(const f16* __restrict__ Wh, int cc, int l31, int g,
                                            f16x8 bf[8]) {
#pragma unroll
  for (int ks = 0; ks < 8; ++ks)
    bf[ks] = *(const f16x8*)(Wh + ((cc * 32 + l31) << 7) + 16 * ks + 8 * g);
}

__device__ __forceinline__ void stage_issue512(const float* __restrict__ X, long M, long base,
                                               int tid, float4 sv[4]) {
#pragma unroll
  for (int kk = 0; kk < 4; ++kk) {
    int i = tid + kk * 512;
    long row = base + (i >> 5);
    long gr = row < M ? row : (M - 1);
    sv[kk] = *(const float4*)(X + gr * DIM + (i & 31) * 4);
  }
}

__device__ __forceinline__ void stage_write512(const float4 sv[4], int tid,
                                               f16* __restrict__ lds) {
#pragma unroll
  for (int kk = 0; kk < 4; ++kk) {
    int i = tid + kk * 512;
    int r = i >> 5, s8 = i & 31;
    f16x4 h;
    h[0] = (f16)sv[kk].x; h[1] = (f16)sv[kk].y; h[2] = (f16)sv[kk].z; h[3] = (f16)sv[kk].w;
    *(f16x4*)(lds + r * 128 + (((s8 >> 1) ^ (r & 15)) << 3) + ((s8 & 1) << 2)) = h;
  }
}

__device__ __forceinline__ void mfma1(const f16* __restrict__ A, int lr, int g,
                                      const f16x8 bf[8], f32x16& acc) {
#pragma unroll
  for (int k = 0; k < 16; ++k) acc[k] = 0.0f;
#pragma unroll
  for (int ks = 0; ks < 8; ++ks) {
    f16x8 a = *(const f16x8*)(A + lr * 128 + (((2 * ks + g) ^ (lr & 15)) << 3));
    acc = __builtin_amdgcn_mfma_f32_32x32x16_f16(a, bf[ks], acc, 0, 0, 0);
  }
}

template <int HALF_OUT>
__device__ __forceinline__ void gemm_store1(const f32x16& acc, long M,
                                            const float* __restrict__ Bv,
                                            void* __restrict__ OUT,
                                            long tile0, int rc, int cc, int l31, int g) {
  int col = cc * 32 + l31;
  float bv = Bv[col];
#pragma unroll
  for (int r = 0; r < 16; ++r) {
    long gm = tile0 + rc * 32 + ((r & 3) + 8 * (r >> 2) + 4 * g);
    if (gm < M) {
      float v = acc[r] + bv;
      if (HALF_OUT) ((f16*)OUT)[gm * DIM + col] = (f16)v;
      else          ((float*)OUT)[gm * DIM + col] = v;
    }
  }
}

// ---------------- fused big GEMMs, 512 threads, one tile per block ----------------
// blocks 0..781: node4 path. blocks 782..13281: edge path, NATURAL order both sides
// (sequential EA reads AND sequential emat writes — pure streaming; the dst
//  permutation moved into attn_ln's emat row reads).
__global__ __launch_bounds__(512, 4) void big_gemms(const float* __restrict__ X,
    const float* __restrict__ EA,
    const f16* __restrict__ WhAll,
    const float* __restrict__ bq, const float* __restrict__ bk,
    const float* __restrict__ bv_, const float* __restrict__ bs, const float* __restrict__ be,
    f16* __restrict__ Q, f16* __restrict__ K, f16* __restrict__ V, float* __restrict__ S,
    f16* __restrict__ emat) {
  __shared__ f16 lbuf[64 * 128];      // 16 KB
  int tid = threadIdx.x;
  int lane = tid & 63, w = tid >> 6;
  int rc = w >> 2, cc = w & 3, l31 = lane & 31, g = lane >> 5;
  int lr = rc * 32 + l31;

  if (blockIdx.x < NODE_TILES) {
    long tile0 = (long)blockIdx.x * 64;
    float4 sv[4];
    stage_issue512(X, N_NODES, tile0, tid, sv);
    stage_write512(sv, tid, lbuf);
    __syncthreads();
#pragma unroll 1
    for (int mat = 0; mat < 4; ++mat) {
      f16x8 bf[8];
      load_wfrag1(WhAll + mat * 16384, cc, l31, g, bf);
      f32x16 acc;
      mfma1(lbuf, lr, g, bf, acc);
      if (mat == 0)      gemm_store1<1>(acc, N_NODES, bq, Q, tile0, rc, cc, l31, g);
      else if (mat == 1) gemm_store1<1>(acc, N_NODES, bk, K, tile0, rc, cc, l31, g);
      else if (mat == 2) gemm_store1<1>(acc, N_NODES, bv_, V, tile0, rc, cc, l31, g);
      else               gemm_store1<0>(acc, N_NODES, bs, S, tile0, rc, cc, l31, g);
    }
    return;
  }

  // ---- edge path: pure streaming ----
  long tile0 = (long)(blockIdx.x - NODE_TILES) * 64;
  float4 sv[4];
  stage_issue512(EA, (long)N_EDGES, tile0, tid, sv);
  stage_write512(sv, tid, lbuf);
  __syncthreads();
  f16x8 bf[8];
  load_wfrag1(WhAll + 4 * 16384, cc, l31, g, bf);   // L2-hot
  f32x16 acc;
  mfma1(lbuf, lr, g, bf, acc);
  gemm_store1<1>(acc, (long)N_EDGES, be, emat, tile0, rc, cc, l31, g);
}

// ---------------- fused MLP + LN2 (single 32 KB LDS, phase-aliased) ----------------
__global__ __launch_bounds__(256) void mlp_ln(const float* __restrict__ X,
    const f16* __restrict__ W1h, const float* __restrict__ b1,
    const f16* __restrict__ W2h, const float* __restrict__ b2,
    const float* __restrict__ gv, const float* __restrict__ bv,
    float* __restrict__ outp) {
  __shared__ float smem[64 * 128];    // 32 KB
  f16* xs = (f16*)smem;               // first 16 KB
  f16* hs = (f16*)smem + 64 * 128;    // second 16 KB
  float* wbuf = smem;                 // full 32 KB
  int tid = threadIdx.x;
  int lane = tid & 63, w = tid >> 6;
  int rc = w >> 1, ch = w & 1, l31 = lane & 31, g = lane >> 5;
  int t = blockIdx.x;
  if (t >= NODE_TILES) return;
  long tile0 = (long)t * 64;
  int lr = rc * 32 + l31;

  float4 sv[8];
  stage_issue(X, N_NODES, tile0, tid, sv);
  f16x8 bf1[2][8];
  load_wfrag(W1h, ch, l31, g, bf1);
  stage_write(sv, tid, xs);
  __syncthreads();

  f32x16 acc[2];
  mfma_lds_g(xs, lr, g, bf1, acc);
  f16x8 bf2[2][8];
  load_wfrag(W2h, ch, l31, g, bf2);

#pragma unroll
  for (int c = 0; c < 2; ++c) {
    int col = ch * 64 + c * 32 + l31;
    float bb = b1[col];
#pragma unroll
    for (int r = 0; r < 16; ++r) {
      int row = rc * 32 + (r & 3) + 8 * (r >> 2) + 4 * g;
      float v = acc[c][r] + bb;
      v = v / (1.0f + __expf(-v));
      hs[row * 128 + (((col >> 3) ^ (row & 15)) << 3) + (col & 7)] = (f16)v;
    }
  }
  __syncthreads();

  f32x16 a2[2];
  mfma_lds_g(hs, lr, g, bf2, a2);
  __syncthreads();

#pragma unroll
  for (int c = 0; c < 2; ++c) {
    int col = ch * 64 + c * 32 + l31;
    float bb = b2[col];
#pragma unroll
    for (int r = 0; r < 16; ++r) {
      int row = rc * 32 + (r & 3) + 8 * (r >> 2) + 4 * g;
      wbuf[row * 128 + col] = a2[c][r] + bb;
    }
  }
  __syncthreads();

  float2 gg = *(const float2*)(gv + 2 * lane);
  float2 bb2 = *(const float2*)(bv + 2 * lane);
#pragma unroll 1
  for (int rr = 0; rr < 16; ++rr) {
    int row = w * 16 + rr;
    long gm = tile0 + row;
    if (gm >= N_NODES) break;
    float2 x;
    x.x = wbuf[row * 128 + 2 * lane];
    x.y = wbuf[row * 128 + 2 * lane + 1];
    float sm = x.x + x.y;
    for (int m = 1; m < 64; m <<= 1) sm += __shfl_xor(sm, m);
    float mu = sm * (1.f / 128.f);
    float dx = x.x - mu, dy = x.y - mu;
    float ss = dx * dx + dy * dy;
    for (int m = 1; m < 64; m <<= 1) ss += __shfl_xor(ss, m);
    float r = rsqrtf(ss * (1.f / 128.f) + 1e-5f);
    float2 bs = *(const float2*)(X + gm * DIM + 2 * lane);
    float2 o;
    o.x = bs.x + dx * r * gg.x + bb2.x;
    o.y = bs.y + dy * r * gg.y + bb2.y;
    *(float2*)(outp + gm * DIM + 2 * lane) = o;
  }
}

// ---------------- CSR build (parallel scan) + weight convert fused into hist ----------
__global__ void hist_conv_k(const int* __restrict__ ei, int* __restrict__ counts,
                            const float* __restrict__ a0, const float* __restrict__ a1,
                            const float* __restrict__ a2, const float* __restrict__ a3,
                            const float* __restrict__ a4, const float* __restrict__ a5,
                            const float* __restrict__ a6, f16* __restrict__ dst) {
  long gid = blockIdx.x * 256L + threadIdx.x;
  if (gid < 7 * 16384) {
    int mat = (int)(gid >> 14), el = (int)(gid & 16383);
    const float* s = (mat == 0) ? a0 : (mat == 1) ? a1 : (mat == 2) ? a2 : (mat == 3) ? a3
                   : (mat == 4) ? a4 : (mat == 5) ? a5 : a6;
    dst[gid] = (f16)s[el];
  }
  for (long e = gid; e < N_EDGES; e += 1024L * 256)
    atomicAdd(&counts[ei[N_EDGES + e]], 1);
}

__global__ __launch_bounds__(1024) void blocksum_k(const int* __restrict__ counts,
                                                   int* __restrict__ bsum) {
  __shared__ int sd[1024];
  int t = threadIdx.x, b = blockIdx.x;
  int v = (t < 1000) ? counts[b * 1000 + t] : 0;
  sd[t] = v; __syncthreads();
  for (int off = 512; off > 0; off >>= 1) {
    if (t < off) sd[t] += sd[t + off];
    __syncthreads();
  }
  if (t == 0) bsum[b] = sd[0];
}

__global__ void scan_small(const int* __restrict__ bsum, int* __restrict__ boff,
                           int* __restrict__ offs) {
  if (threadIdx.x == 0) {
    int run = 0;
    for (int b = 0; b < SCAN_NB; ++b) { boff[b] = run; run += bsum[b]; }
    boff[SCAN_NB] = run;
    offs[N_NODES] = run;
  }
}

__global__ __launch_bounds__(1024) void expand_k(const int* __restrict__ counts,
                                                 const int* __restrict__ boff,
                                                 int* __restrict__ offs, int* __restrict__ cursor) {
  __shared__ int sd[1024];
  int t = threadIdx.x, b = blockIdx.x;
  int v = (t < 1000) ? counts[b * 1000 + t] : 0;
  sd[t] = v; __syncthreads();
  for (int off = 1; off < 1024; off <<= 1) {
    int x = (t >= off) ? sd[t - off] : 0;
    __syncthreads();
    sd[t] += x;
    __syncthreads();
  }
  if (t < 1000) {
    int o = boff[b] + sd[t] - v;
    int idx = b * 1000 + t;
    offs[idx] = o;
    cursor[idx] = o;
  }
}

// scatter: meta[pos] = (src node, edge id) for dst-sorted position pos
__global__ void scatter_k(const int* __restrict__ ei, int* __restrict__ cursor,
                          int2* __restrict__ meta) {
  for (long e = blockIdx.x * (long)blockDim.x + threadIdx.x; e < N_EDGES;
       e += (long)gridDim.x * blockDim.x) {
    int d = ei[N_EDGES + e];
    int pos = atomicAdd(&cursor[d], 1);
    meta[pos] = make_int2(ei[e], (int)e);
  }
}

// ---------------- fused attention + softmax + LN1, 4 edges/iteration ----------------
// emat in NATURAL edge order: row loads are random 256B (the permutation lives here,
// overlapped with K/V gathers + exp/FMA). meta[pos]=(src,eid) streams sequentially.
__global__ __launch_bounds__(256) void attn_ln(const int* __restrict__ offs,
    const int2* __restrict__ meta, const f16* __restrict__ emat, const f16* __restrict__ Qn,
    const f16* __restrict__ Kn, const f16* __restrict__ Vn,
    const float* __restrict__ Skip, const float* __restrict__ base,
    const float* __restrict__ gv, const float* __restrict__ bv,
    float* __restrict__ outp) {
  int n = blockIdx.x * 4 + (threadIdx.x >> 6);
  if (n >= N_NODES) return;
  int lane = threadIdx.x & 63;
  int grp = lane >> 4, li = lane & 15;
  int c8 = 8 * li;

  float q[8];
  {
    f16x8 qv = *(const f16x8*)(Qn + (long)n * DIM + c8);
#pragma unroll
    for (int k = 0; k < 8; ++k) q[k] = (float)qv[k];
  }

  int rs = offs[n], re = offs[n + 1];
  float a[8];
#pragma unroll
  for (int k = 0; k < 8; ++k) a[k] = 0.f;
  float den = 0.f;

  if (rs < re) {
    int e0 = rs + grp;
    int2 mCur = meta[(e0 < re) ? e0 : (re - 1)];
    for (int i = rs; i < re; i += 4) {
      int ei_ = i + grp;
      bool valid = ei_ < re;
      int s = mCur.x;
      long eid = mCur.y;
      int en = ei_ + 4;
      mCur = meta[(en < re) ? en : (re - 1)];
      f16x8 e8 = *(const f16x8*)(emat + eid * DIM + c8);
      f16x8 k8 = *(const f16x8*)(Kn + (long)s * DIM + c8);
      f16x8 v8 = *(const f16x8*)(Vn + (long)s * DIM + c8);
      float p = 0.f;
#pragma unroll
      for (int k = 0; k < 8; ++k) p += q[k] * ((float)k8[k] + (float)e8[k]);
      p += __shfl_xor(p, 1);
      float ex = valid ? __expf(p * 0.25f) : 0.f;
      den += ex;
#pragma unroll
      for (int k = 0; k < 8; ++k) a[k] += ex * ((float)e8[k] + (float)v8[k]);
    }
  }
#pragma unroll
  for (int k = 0; k < 8; ++k) {
    a[k] += __shfl_xor(a[k], 16);
    a[k] += __shfl_xor(a[k], 32);
  }
  den += __shfl_xor(den, 16);
  den += __shfl_xor(den, 32);

  float inv = 1.f / (den + 1e-16f);
  float x[8];
  {
    float4 sk0 = *(const float4*)(Skip + (long)n * DIM + c8);
    float4 sk1 = *(const float4*)(Skip + (long)n * DIM + c8 + 4);
    x[0] = a[0] * inv + sk0.x; x[1] = a[1] * inv + sk0.y;
    x[2] = a[2] * inv + sk0.z; x[3] = a[3] * inv + sk0.w;
    x[4] = a[4] * inv + sk1.x; x[5] = a[5] * inv + sk1.y;
    x[6] = a[6] * inv + sk1.z; x[7] = a[7] * inv + sk1.w;
  }

  float sm = 0.f;
#pragma unroll
  for (int k = 0; k < 8; ++k) sm += x[k];
  for (int m = 1; m < 16; m <<= 1) sm += __shfl_xor(sm, m);
  float mu = sm * (1.f / 128.f);
  float d[8], ss = 0.f;
#pragma unroll
  for (int k = 0; k < 8; ++k) { d[k] = x[k] - mu; ss += d[k] * d[k]; }
  for (int m = 1; m < 16; m <<= 1) ss += __shfl_xor(ss, m);
  float r = rsqrtf(ss * (1.f / 128.f) + 1e-5f);

  if (grp == 0) {
    float4 g0 = *(const float4*)(gv + c8);
    float4 g1 = *(const float4*)(gv + c8 + 4);
    float4 b0 = *(const float4*)(bv + c8);
    float4 b1 = *(const float4*)(bv + c8 + 4);
    float4 s0 = *(const float4*)(base + (long)n * DIM + c8);
    float4 s1 = *(const float4*)(base + (long)n * DIM + c8 + 4);
    float4 o0, o1;
    o0.x = s0.x + d[0] * r * g0.x + b0.x;
    o0.y = s0.y + d[1] * r * g0.y + b0.y;
    o0.z = s0.z + d[2] * r * g0.z + b0.z;
    o0.w = s0.w + d[3] * r * g0.w + b0.w;
    o1.x = s1.x + d[4] * r * g1.x + b1.x;
    o1.y = s1.y + d[5] * r * g1.y + b1.y;
    o1.z = s1.z + d[6] * r * g1.z + b1.z;
    o1.w = s1.w + d[7] * r * g1.w + b1.w;
    *(float4*)(outp + (long)n * DIM + c8) = o0;
    *(float4*)(outp + (long)n * DIM + c8 + 4) = o1;
  }
}

// ---------------- launch ----------------
extern "C" void kernel_launch(void* const* d_in, const int* in_sizes, int n_in,
                              void* d_out, int out_size, void* d_ws, size_t ws_size,
                              hipStream_t stream) {
  (void)in_sizes; (void)n_in; (void)out_size; (void)ws_size;
  const int*   ei  = (const int*)d_in[0];
  const float* x0  = (const float*)d_in[1];
  const float* ea  = (const float*)d_in[2];
  const float* Wq  = (const float*)d_in[3];  const float* bq = (const float*)d_in[4];
  const float* Wk  = (const float*)d_in[5];  const float* bk = (const float*)d_in[6];
  const float* Wv  = (const float*)d_in[7];  const float* bv = (const float*)d_in[8];
  const float* We  = (const float*)d_in[9];  const float* be = (const float*)d_in[10];
  const float* Wsk = (const float*)d_in[11]; const float* bsk = (const float*)d_in[12];
  const float* W1  = (const float*)d_in[13]; const float* b1 = (const float*)d_in[14];
  const float* W2  = (const float*)d_in[15]; const float* b2 = (const float*)d_in[16];
  const float* g1  = (const float*)d_in[17]; const float* lb1 = (const float*)d_in[18];
  const float* g2  = (const float*)d_in[19]; const float* lb2 = (const float*)d_in[20];

  char* ws = (char*)d_ws;
  f16*   Qn     = (f16*)(ws + 0);              // 12.8M
  f16*   Kn     = (f16*)(ws + 12800000L);      // 12.8M
  f16*   Vn     = (f16*)(ws + 25600000L);      // 12.8M
  float* Skip   = (float*)(ws + 38400000L);    // 25.6M -> 64,000,000
  int*   offs   = (int*)(ws + 64000000L);      // 200,192
  int*   cursor = (int*)(ws + 64200192L);      // 200,192
  int*   counts = (int*)(ws + 64429568L);      // 200,000
  int*   bsum   = (int*)(ws + 64629760L);      // 512 B
  int*   boff   = bsum + 64;
  int2*  meta   = (int2*)(ws + 64630272L);     // 6.4M
  f16*   emat   = (f16*)(ws + 71030272L);      // 204.8M (NATURAL edge order)
  float* node1  = (float*)(ws + 275830272L);   // 25.6M
  f16*   WhAll  = (f16*)(ws + 301430272L);     // 229,376 own slot

  (void)hipMemsetAsync(counts, 0, N_NODES * sizeof(int), stream);
  hist_conv_k<<<1024, 256, 0, stream>>>(ei, counts, Wq, Wk, Wv, Wsk, We, W1, W2, WhAll);
  blocksum_k<<<SCAN_NB, 1024, 0, stream>>>(counts, bsum);
  scan_small<<<1, 64, 0, stream>>>(bsum, boff, offs);
  expand_k<<<SCAN_NB, 1024, 0, stream>>>(counts, boff, offs, cursor);
  scatter_k<<<1024, 256, 0, stream>>>(ei, cursor, meta);

  big_gemms<<<NODE_TILES + EDGE_TILES, 512, 0, stream>>>(
      x0, ea, WhAll, bq, bk, bv, bsk, be, Qn, Kn, Vn, Skip, emat);
  attn_ln<<<12500, 256, 0, stream>>>(offs, meta, emat, Qn, Kn, Vn, Skip, x0, g1, lb1, node1);
  mlp_ln<<<NODE_TILES, 256, 0, stream>>>(node1, WhAll + 5 * 16384, b1,
                                         WhAll + 6 * 16384, b2, g2, lb2, (float*)d_out);
}